// Round 13
// baseline (2237.328 us; speedup 1.0000x reference)
//
#include <hip/hip_runtime.h>
#include <math.h>

typedef unsigned short ushort_t;
typedef unsigned int uint_t;
typedef unsigned long long ulong_t;
typedef __attribute__((ext_vector_type(8))) short s16x8;
typedef __attribute__((ext_vector_type(4))) float f32x4;

#define BB 8
#define TT 64
#define VV 30000
#define VP 30080
#define EE 256
#define HH 512
#define MM 512
#define UU 32
#define WW 512
#define G3 1536
#define NDB 235
#define NBG 64

// workspace offsets (floats)
#define OFF_GI    0          // 512*1536
#define OFF_YALL  786432     // 512*256
#define OFF_WY    917504     // 512
#define OFF_H0    918016     // 4096
#define OFF_HALL  922112     // 512*512
#define OFF_HU    1184256    // 512*512
#define OFF_HW    1446400    // 512*512
#define OFF_HS    1708544    // 512
#define OFF_HWV   1709056    // 512
#define OFF_P     1709568    // 64*8*32
#define OFF_SW    1725952    // 64*8*512  (sw -> pw in place)
#define OFF_C     1988096    // bf16 64*8*32*512 = 4194304 float slots
#define OFF_E     6182400    // 16384
#define OFF_WV    6198784    // 1024 + 2, pad 1536
#define OFF_PART  6200320    // double buffer 2*4096
#define OFF_LSE   6208512    // 512
#define OFF_WOV   6209024    // bf16 [v][k] 30080*512 = 7700480 float slots
#define OFF_HBT   13909504   // bf16 512*512 = 131072 float slots
#define OFF_SYNC  14040576   // 16384 floats (uint view): gru flags @0 (blk*32),
                             //   dec flags @8192+blk*32, dec go @16000
#define OFF_PC    14056960   // fp32 512 rows x 512 m = 262144
// total 14319104 floats = 57.3 MB

#define DEC_SZ (BB*TT*VV)
#define SUW_OFF DEC_SZ
#define SU_OFF  (DEC_SZ + BB*TT*WW)

__device__ __forceinline__ float sigm(float x){ return 1.0f/(1.0f+__expf(-x)); }
__device__ __forceinline__ ushort_t to_bf16(float f){
  uint_t u = __float_as_uint(f);
  return (ushort_t)((u + 0x7fffu + ((u>>16)&1u)) >> 16);
}

// ---------------- precompute ----------------

template<int TRANSB>
__global__ void __launch_bounds__(256)
k_gemm_b(const float* __restrict__ A, int lda, int aS,
         const float* __restrict__ B, int ldb, int bS,
         const float* __restrict__ bias,
         float* __restrict__ C, int ldc, int cS, int K){
  A += (size_t)blockIdx.z * aS;
  B += (size_t)blockIdx.z * bS;
  C += (size_t)blockIdx.z * cS;
  __shared__ float As[32][65];
  __shared__ float Bs[32][65];
  int tid = threadIdx.x;
  int bx = blockIdx.x, by = blockIdx.y;
  int tx = tid & 15, ty = tid >> 4;
  float acc[4][4] = {};
  for (int k0 = 0; k0 < K; k0 += 32){
    {
      int r = tid >> 2, cbase = (tid & 3) * 8;
      const float* ap = A + (size_t)(by*64 + r)*lda + k0 + cbase;
      #pragma unroll
      for (int i=0;i<8;++i) As[cbase+i][r] = ap[i];
    }
    if (TRANSB){
      int r = tid >> 2, cbase = (tid & 3) * 8;
      const float* bp = B + (size_t)(bx*64 + r)*ldb + k0 + cbase;
      #pragma unroll
      for (int i=0;i<8;++i) Bs[cbase+i][r] = bp[i];
    } else {
      int kk = tid >> 3, cbase = (tid & 7) * 8;
      const float* bp = B + (size_t)(k0 + kk)*ldb + bx*64 + cbase;
      #pragma unroll
      for (int i=0;i<8;++i) Bs[kk][cbase+i] = bp[i];
    }
    __syncthreads();
    #pragma unroll
    for (int kk=0;kk<32;++kk){
      float a0=As[kk][ty*4+0], a1=As[kk][ty*4+1], a2=As[kk][ty*4+2], a3=As[kk][ty*4+3];
      float b0=Bs[kk][tx*4+0], b1=Bs[kk][tx*4+1], b2=Bs[kk][tx*4+2], b3=Bs[kk][tx*4+3];
      acc[0][0]+=a0*b0; acc[0][1]+=a0*b1; acc[0][2]+=a0*b2; acc[0][3]+=a0*b3;
      acc[1][0]+=a1*b0; acc[1][1]+=a1*b1; acc[1][2]+=a1*b2; acc[1][3]+=a1*b3;
      acc[2][0]+=a2*b0; acc[2][1]+=a2*b1; acc[2][2]+=a2*b2; acc[2][3]+=a2*b3;
      acc[3][0]+=a3*b0; acc[3][1]+=a3*b1; acc[3][2]+=a3*b2; acc[3][3]+=a3*b3;
    }
    __syncthreads();
  }
  #pragma unroll
  for (int i=0;i<4;++i){
    int row = by*64 + ty*4 + i;
    #pragma unroll
    for (int j=0;j<4;++j){
      int col = bx*64 + tx*4 + j;
      float v = acc[i][j];
      if (bias) v += bias[col];
      C[(size_t)row*ldc + col] = v;
    }
  }
}

// gather y + wy dot, one block per bt row
__global__ void k_y(const int* __restrict__ target, const float* __restrict__ emb,
                    const float* __restrict__ Wy, float* __restrict__ ws){
  int bt = blockIdx.x;
  int e = threadIdx.x;            // 256 = EE
  __shared__ float r[256];
  int tok = target[bt];
  float v = emb[tok*EE + e];
  ws[OFF_YALL + bt*EE + e] = v;
  r[e] = v * Wy[e];
  __syncthreads();
  for (int s=128; s; s>>=1){ if (e<s) r[e]+=r[e+s]; __syncthreads(); }
  if (e == 0) ws[OFF_WY + bt] = r[0];
}

__global__ void k_h0(const float* __restrict__ u_output, const int* __restrict__ u_len,
                     float* __restrict__ ws){
  int idx = blockIdx.x*256 + threadIdx.x;   // B*H
  int b = idx >> 9; int k = idx & 511;
  int u = u_len[b]-1;
  ws[OFF_H0 + idx] = u_output[(b*UU+u)*MM + k];
}

// WOV[v][k] = bf16(Wo[v][k]) for k<512 (ctx half); rows v>=VV zero. VP rows.
__global__ void __launch_bounds__(256)
k_wovc(const float* __restrict__ Wo, ushort_t* __restrict__ wov){
  int idx8 = blockIdx.x*256 + threadIdx.x;   // VP*512/8 items of 8 elems
  int v = idx8 >> 6;
  int k8 = (idx8 & 63) << 3;
  uint_t u0=0,u1=0,u2=0,u3=0;
  if (v < VV){
    const float* src = Wo + (size_t)v*1024 + k8;
    float4 f0 = *(const float4*)src;
    float4 f1 = *(const float4*)(src+4);
    u0 = (uint_t)to_bf16(f0.x) | ((uint_t)to_bf16(f0.y) << 16);
    u1 = (uint_t)to_bf16(f0.z) | ((uint_t)to_bf16(f0.w) << 16);
    u2 = (uint_t)to_bf16(f1.x) | ((uint_t)to_bf16(f1.y) << 16);
    u3 = (uint_t)to_bf16(f1.z) | ((uint_t)to_bf16(f1.w) << 16);
  }
  uint4 pk = make_uint4(u0,u1,u2,u3);
  *(uint4*)(wov + (size_t)idx8*8) = pk;
}

// wv[k] = sum_v Wo[v][k]*Wd[v]; wv[1024]=bo.Wd; wv[1025]=sum Wd
__global__ void __launch_bounds__(256)
k_wv(const float* __restrict__ Wo, const float* __restrict__ bo,
     const float* __restrict__ Wd, float* __restrict__ wv){
  __shared__ float wds[128];
  __shared__ float red[256];
  int tid = threadIdx.x;
  int v0 = blockIdx.x*128;
  float pbo=0.f, pwd=0.f;
  if (tid < 128){
    int v = v0 + tid;
    float wd = (v<VV)? Wd[v] : 0.f;
    wds[tid] = wd;
    pbo = wd * ((v<VV)? bo[v] : 0.f);
    pwd = wd;
  }
  __syncthreads();
  float4 acc = {0,0,0,0};
  int nmax = (v0 + 128 <= VV) ? 128 : (VV - v0);
  for (int i=0;i<nmax;++i){
    float wd = wds[i];
    float4 w4 = *(const float4*)(Wo + (size_t)(v0+i)*1024 + tid*4);
    acc.x += wd*w4.x; acc.y += wd*w4.y; acc.z += wd*w4.z; acc.w += wd*w4.w;
  }
  atomicAdd(&wv[tid*4+0], acc.x);
  atomicAdd(&wv[tid*4+1], acc.y);
  atomicAdd(&wv[tid*4+2], acc.z);
  atomicAdd(&wv[tid*4+3], acc.w);
  red[tid] = pbo; __syncthreads();
  for (int s=128; s; s>>=1){ if (tid<s) red[tid]+=red[tid+s]; __syncthreads(); }
  if (tid==0) atomicAdd(&wv[1024], red[0]);
  __syncthreads();
  red[tid] = pwd; __syncthreads();
  for (int s=128; s; s>>=1){ if (tid<s) red[tid]+=red[tid+s]; __syncthreads(); }
  if (tid==0) atomicAdd(&wv[1025], red[0]);
}

// ---------------- persistent GRU chain (64 x 1024, split-K, single-hop) ----------------

__global__ void __launch_bounds__(1024)
k_gru_persist(const float* __restrict__ W_hh, const float* __restrict__ b_hh,
              float* __restrict__ ws){
  uint_t* flags = (uint_t*)(ws + OFF_SYNC);
  int tid  = threadIdx.x;
  int wid  = tid >> 6;          // 0..15
  int lane = tid & 63;
  int half = wid >> 3;          // 0/1: K-half
  int kl   = wid & 7;           // k-local 0..7
  int k    = blockIdx.x*8 + kl; // 0..511
  const float* gi_all = ws + OFF_GI;
  const float* wr = W_hh + (size_t)k*HH;
  const float* wz = W_hh + (size_t)(HH+k)*HH;
  const float* wn = W_hh + (size_t)(2*HH+k)*HH;
  __shared__ float red[16][24];

  for (int t=0; t<TT; ++t){
    const float* hin = (t==0) ? (ws+OFF_H0) : (ws+OFF_HALL + (size_t)(t-1)*4096);
    float* hout = ws + OFF_HALL + (size_t)t*4096;
    float pr[8], pz[8], pn[8];
    #pragma unroll
    for (int b=0;b<8;++b){ pr[b]=0.f; pz[b]=0.f; pn[b]=0.f; }
    int kk0 = half*256 + lane;
    #pragma unroll
    for (int it=0; it<4; ++it){
      int kk = kk0 + it*64;
      float w1 = wr[kk], w2 = wz[kk], w3 = wn[kk];
      #pragma unroll
      for (int b=0;b<8;++b){
        float hv = hin[b*HH+kk];
        pr[b] += hv*w1; pz[b] += hv*w2; pn[b] += hv*w3;
      }
    }
    #pragma unroll
    for (int off=32; off; off>>=1){
      #pragma unroll
      for (int b=0;b<8;++b){
        pr[b] += __shfl_xor(pr[b],off);
        pz[b] += __shfl_xor(pz[b],off);
        pn[b] += __shfl_xor(pn[b],off);
      }
    }
    if (lane == 0){
      #pragma unroll
      for (int b=0;b<8;++b){
        red[wid][b]    = pr[b];
        red[wid][8+b]  = pz[b];
        red[wid][16+b] = pn[b];
      }
    }
    __syncthreads();
    if (tid < 64){
      int klx = tid >> 3, b = tid & 7;
      int k2 = blockIdx.x*8 + klx;
      float prs = red[klx][b]    + red[8+klx][b];
      float pzs = red[klx][8+b]  + red[8+klx][8+b];
      float pns = red[klx][16+b] + red[8+klx][16+b];
      const float* gi = gi_all + (b*TT + t)*G3;
      float r = sigm(gi[k2]      + prs + b_hh[k2]);
      float z = sigm(gi[HH+k2]   + pzs + b_hh[HH+k2]);
      float n = tanhf(gi[2*HH+k2] + r*(pns + b_hh[2*HH+k2]));
      hout[b*HH+k2] = (1.f-z)*n + z*hin[b*HH+k2];
    }
    // single-hop poll-all barrier
    __syncthreads();
    if (tid == 0)
      __hip_atomic_store(&flags[blockIdx.x*32], (uint_t)(t+1), __ATOMIC_RELEASE, __HIP_MEMORY_SCOPE_AGENT);
    if (tid < NBG){
      while (__hip_atomic_load(&flags[tid*32], __ATOMIC_RELAXED, __HIP_MEMORY_SCOPE_AGENT) < (uint_t)(t+1))
        __builtin_amdgcn_s_sleep(1);
    }
    __syncthreads();
  }
  // tail: write hbt (bf16 of HALL)
  {
    ushort_t* hbt = (ushort_t*)(ws + OFF_HBT);
    int base = (blockIdx.x*1024 + tid)*4;
    #pragma unroll
    for (int i=0;i<4;++i) hbt[base+i] = to_bf16(ws[OFF_HALL + base + i]);
  }
}

// ---------------- h-half logits via MFMA ----------------

__global__ void __launch_bounds__(256)
k_lh_mfma(const float* __restrict__ Wo, const float* __restrict__ bo,
          const ushort_t* __restrict__ hbt, float* __restrict__ out){
  int tid = threadIdx.x;
  int wv = tid >> 6, l = tid & 63;
  int lm = l & 15, lg = l >> 4;
  int vbase = blockIdx.x*128 + wv*32;   // 2 v-subtiles of 16
  int rbase = blockIdx.y*128;           // 8 row-subtiles of 16
  f32x4 acc[2][8];
  #pragma unroll
  for (int s=0;s<2;++s)
    #pragma unroll
    for (int rt=0;rt<8;++rt) acc[s][rt] = (f32x4){0.f,0.f,0.f,0.f};

  for (int k0 = 0; k0 < 512; k0 += 32){
    int kk = k0 + lg*8;
    union { uint_t u[4]; s16x8 s; } af[2];
    #pragma unroll
    for (int s=0;s<2;++s){
      int v = vbase + s*16 + lm; if (v >= VV) v = VV-1;
      const float* ap = Wo + (size_t)v*1024 + 512 + kk;
      float4 f0 = *(const float4*)ap;
      float4 f1 = *(const float4*)(ap+4);
      af[s].u[0] = ((__float_as_uint(f0.x)+0x8000u)>>16) | ((__float_as_uint(f0.y)+0x8000u) & 0xffff0000u);
      af[s].u[1] = ((__float_as_uint(f0.z)+0x8000u)>>16) | ((__float_as_uint(f0.w)+0x8000u) & 0xffff0000u);
      af[s].u[2] = ((__float_as_uint(f1.x)+0x8000u)>>16) | ((__float_as_uint(f1.y)+0x8000u) & 0xffff0000u);
      af[s].u[3] = ((__float_as_uint(f1.z)+0x8000u)>>16) | ((__float_as_uint(f1.w)+0x8000u) & 0xffff0000u);
    }
    #pragma unroll
    for (int rt=0;rt<8;++rt){
      const ushort_t* bp = hbt + (size_t)(rbase + rt*16 + lm)*HH + kk;
      s16x8 bf = *(const s16x8*)bp;
      acc[0][rt] = __builtin_amdgcn_mfma_f32_16x16x32_bf16(af[0].s, bf, acc[0][rt], 0, 0, 0);
      acc[1][rt] = __builtin_amdgcn_mfma_f32_16x16x32_bf16(af[1].s, bf, acc[1][rt], 0, 0, 0);
    }
  }
  float bv[2][4];
  #pragma unroll
  for (int s=0;s<2;++s)
    #pragma unroll
    for (int r=0;r<4;++r){
      int v = vbase + s*16 + lg*4 + r;
      bv[s][r] = (v < VV) ? bo[v] : 0.f;
    }
  #pragma unroll
  for (int rt=0;rt<8;++rt){
    int row = rbase + rt*16 + lm;
    float* orow = out + (size_t)((row&7)*TT + (row>>3))*VV;
    #pragma unroll
    for (int s=0;s<2;++s){
      #pragma unroll
      for (int r=0;r<4;++r){
        int v = vbase + s*16 + lg*4 + r;
        if (v < VV) orow[v] = acc[s][rt][r] + bv[s][r];
      }
    }
  }
}

// ---------------- batched post-h ----------------

__global__ void k_hdots(const float* __restrict__ Ws, float* __restrict__ ws){
  int wid  = blockIdx.x*4 + (threadIdx.x>>6);  // 1024 waves
  int lane = threadIdx.x & 63;
  int row = wid >> 1, which = wid & 1;
  const float* h = ws + OFF_HALL + row*HH;
  const float* src = which ? (ws + OFF_WV + 512) : Ws;
  float acc = 0.f;
  for (int k=lane; k<HH; k+=64) acc += h[k]*src[k];
  for (int off=32; off; off>>=1) acc += __shfl_xor(acc, off);
  if (lane == 0) (which ? ws+OFF_HWV : ws+OFF_HS)[row] = acc;
}

__global__ void k_p(const float* __restrict__ u_output, const int* __restrict__ u_len,
                    float* __restrict__ ws){
  int row = blockIdx.x;          // t*8+b
  int b = row & 7;
  int tid = threadIdx.x;
  __shared__ float su_s[UU];
  {
    int u = tid >> 3, l8 = tid & 7;
    const float* hu = ws + OFF_HU + row*512;
    const float* uo = u_output + (size_t)(b*UU + u)*MM;
    float acc = 0.f;
    for (int m=l8; m<MM; m+=8) acc += hu[m]*uo[m];
    acc += __shfl_xor(acc,1); acc += __shfl_xor(acc,2); acc += __shfl_xor(acc,4);
    if (l8 == 0) su_s[u] = acc;
  }
  __syncthreads();
  if (tid < 32){
    int ul = u_len[b];
    float sv = su_s[tid];
    bool valid = tid < ul;
    float mv = valid ? sv : -1e30f;
    for (int off=16; off; off>>=1) mv = fmaxf(mv, __shfl_xor(mv, off));
    float e = valid ? __expf(sv - mv) : 0.f;
    float ssum = e;
    for (int off=16; off; off>>=1) ssum += __shfl_xor(ssum, off);
    ws[OFF_P + row*UU + tid] = e/ssum;
  }
}

__global__ void k_pw(const int* __restrict__ word2utt, const int* __restrict__ w_len,
                     float* __restrict__ ws){
  int row = blockIdx.x;  // t*8+b
  int b = row & 7;
  int tid = threadIdx.x;
  __shared__ float sarr[WW];
  __shared__ int   seg[WW];
  __shared__ float marr[UU], darr[UU];
  int wl = w_len[b];
  float* swrow = ws + OFF_SW + row*WW;
  for (int w=tid; w<WW; w+=256){ sarr[w] = swrow[w]; seg[w] = word2utt[b*WW+w]; }
  __syncthreads();
  {
    int g = tid>>3, l8 = tid&7;
    float mv = -1e30f;
    for (int w=l8; w<wl; w+=8) if (seg[w]==g) mv = fmaxf(mv, sarr[w]);
    mv = fmaxf(mv, __shfl_xor(mv,1)); mv = fmaxf(mv, __shfl_xor(mv,2)); mv = fmaxf(mv, __shfl_xor(mv,4));
    float d = 0.f;
    for (int w=l8; w<wl; w+=8) if (seg[w]==g) d += __expf(sarr[w]-mv);
    d += __shfl_xor(d,1); d += __shfl_xor(d,2); d += __shfl_xor(d,4);
    if (l8 == 0){ marr[g]=mv; darr[g]=d; }
  }
  __syncthreads();
  for (int w=tid; w<WW; w+=256){
    float val = 0.f;
    if (w < wl){ int u = seg[w]; val = __expf(sarr[w]-marr[u])/darr[u]; }
    swrow[w] = val;
  }
}

// C (bf16), E, and PC = p . C  (PC folded in)
__global__ void __launch_bounds__(256)
k_C(const float* __restrict__ w_output, const int* __restrict__ w_len,
    const int* __restrict__ u_len, const int* __restrict__ word2utt,
    float* __restrict__ ws){
  int row = blockIdx.x;  // t*8+b
  int b = row & 7;
  int tid = threadIdx.x;
  __shared__ float pws[WW];
  __shared__ int   seg[WW];
  __shared__ int   st[UU], en[UU];
  __shared__ float wvs[512];
  __shared__ float parr[UU];
  __shared__ float red32[UU][4];
  int wl = w_len[b], ul = u_len[b];
  const float* pwrow = ws + OFF_SW + row*WW;
  for (int w=tid; w<WW; w+=256){ pws[w] = pwrow[w]; seg[w] = word2utt[b*WW+w]; }
  for (int m=tid; m<512; m+=256) wvs[m] = ws[OFF_WV + m];
  if (tid < UU){ st[tid]=0; en[tid]=0; parr[tid] = ws[OFF_P + row*UU + tid]; }
  __syncthreads();
  for (int w=tid; w<wl; w+=256){
    int s = seg[w];
    if (w==0 || seg[w-1]!=s) st[s]=w;
    if (w==wl-1 || seg[w+1]!=s) en[s]=w+1;
  }
  __syncthreads();
  ushort_t* Cu = (ushort_t*)(ws + OFF_C);
  int m0 = tid, m1 = tid + 256;
  int lane = tid & 63, wvi = tid >> 6;
  float pc0 = 0.f, pc1 = 0.f;
  for (int u=0; u<UU; ++u){
    float acc0=0.f, acc1=0.f;
    if (u < ul){
      int s = st[u], e = en[u];
      for (int w=s; w<e; ++w){
        float p = pws[w];
        const float* wo = w_output + ((size_t)(b*WW+w))*MM;
        acc0 += p*wo[m0];
        acc1 += p*wo[m1];
      }
    }
    size_t cbase = ((size_t)row*UU + u)*512;
    Cu[cbase + m0] = to_bf16(acc0);
    Cu[cbase + m1] = to_bf16(acc1);
    float pu = parr[u];
    pc0 += pu*acc0; pc1 += pu*acc1;
    float part = acc0*wvs[m0] + acc1*wvs[m1];
    #pragma unroll
    for (int off=32; off; off>>=1) part += __shfl_xor(part, off);
    if (lane == 0) red32[u][wvi] = part;
  }
  ws[OFF_PC + (size_t)row*512 + m0] = pc0;
  ws[OFF_PC + (size_t)row*512 + m1] = pc1;
  __syncthreads();
  if (tid < UU)
    ws[OFF_E + row*UU + tid] = red32[tid][0]+red32[tid][1]+red32[tid][2]+red32[tid][3];
}

// -------- persistent decode: 235 workers + 1 leader; pipelined MFMA --------

__global__ void __launch_bounds__(512)
k_decode_persist(const int* __restrict__ u_len, const float* __restrict__ bs,
                 const ushort_t* __restrict__ wov,
                 float* __restrict__ ws, float* __restrict__ out){
  int bid = blockIdx.x;
  int tid = threadIdx.x;
  uint_t* sy    = (uint_t*)(ws + OFF_SYNC);
  uint_t* flags = sy + 8192;
  uint_t* go    = sy + 16000;

  // ---------- leader block ----------
  if (bid == NDB){
    int wid = tid >> 6, l = tid & 63;   // wid = b
    for (int t=0; t<TT; ++t){
      if (tid < NDB){
        while (__hip_atomic_load(&flags[tid*32], __ATOMIC_RELAXED, __HIP_MEMORY_SCOPE_AGENT) < (uint_t)(t+1))
          __builtin_amdgcn_s_sleep(1);
      }
      __syncthreads();
      {
        const ulong_t* partq = (const ulong_t*)(ws + OFF_PART + (t&1)*4096);
        float ma = -1e30f, sa = 0.f;
        #pragma unroll
        for (int it=0; it<4; ++it){
          int i = l + it*64;
          if (i < NDB){
            ulong_t pq = __hip_atomic_load(&partq[i*8 + wid], __ATOMIC_RELAXED, __HIP_MEMORY_SCOPE_AGENT);
            float m = __uint_as_float((uint_t)pq);
            float s = __uint_as_float((uint_t)(pq >> 32));
            float mm = fmaxf(ma, m);
            sa = sa*__expf(ma-mm) + s*__expf(m-mm);
            ma = mm;
          }
        }
        #pragma unroll
        for (int off=32; off; off>>=1){
          float mo = __shfl_xor(ma, off);
          float so = __shfl_xor(sa, off);
          float mm = fmaxf(ma, mo);
          sa = sa*__expf(ma-mm) + so*__expf(mo-mm);
          ma = mm;
        }
        if (l == 0)
          __hip_atomic_store((float*)(ws + OFF_LSE + t*8 + wid), ma + logf(sa),
                             __ATOMIC_RELAXED, __HIP_MEMORY_SCOPE_AGENT);
      }
      __syncthreads();
      if (tid == 0)
        __hip_atomic_store(go, (uint_t)(t+1), __ATOMIC_RELEASE, __HIP_MEMORY_SCOPE_AGENT);
    }
    return;
  }

  // ---------- worker ----------
  __shared__ float suL[8][32];
  __shared__ float qbufL[8], lseL[8], gamL[8], s2L[8];
  __shared__ uint_t cbPC[16*260];
  __shared__ uint_t cbEC[16*260];
  __shared__ float2 wred[8][8];
  __shared__ float cst[4];
  if (tid == 0){ cst[0]=bs[0]; cst[1]=ws[OFF_WV+1024]; cst[2]=ws[OFF_WV+1025]; }
  if (tid < 8){ qbufL[tid]=0.f; lseL[tid]=0.f; s2L[tid]=1.f; }
  if (tid < 256) suL[tid>>5][tid&31] = 0.f;
  for (int i=tid; i<8*260; i+=512){ cbPC[8*260 + i] = 0u; cbEC[8*260 + i] = 0u; }
  __syncthreads();

  int wid = tid >> 6, l = tid & 63;
  int lm = l & 15, lgp = l >> 4;
  int vbase = bid*128 + wid*16;
  const ushort_t* ap0 = wov + (size_t)(vbase + lm)*512 + lgp*8;
  const uint_t* cbrowP = cbPC + lm*260 + lgp*4;
  const uint_t* cbrowE = cbEC + lm*260 + lgp*4;

  f32x4 LPC = {0.f,0.f,0.f,0.f};
  f32x4 LEC = {0.f,0.f,0.f,0.f};
  float Lh4[4] = {0.f,0.f,0.f,0.f};

  // prologue: cbPC(0) from PC row 0; LEC(0)=0; MFMA LPC(0); preload Lh(0)
  {
    int b = tid >> 6, l64 = tid & 63;
    const float* PCrow = ws + OFF_PC + (size_t)(b)*512 + l64*8;
    float4 p0 = *(const float4*)PCrow;
    float4 p1 = *(const float4*)(PCrow + 4);
    cbPC[b*260 + l64*4 + 0] = (uint_t)to_bf16(p0.x) | ((uint_t)to_bf16(p0.y) << 16);
    cbPC[b*260 + l64*4 + 1] = (uint_t)to_bf16(p0.z) | ((uint_t)to_bf16(p0.w) << 16);
    cbPC[b*260 + l64*4 + 2] = (uint_t)to_bf16(p1.x) | ((uint_t)to_bf16(p1.y) << 16);
    cbPC[b*260 + l64*4 + 3] = (uint_t)to_bf16(p1.z) | ((uint_t)to_bf16(p1.w) << 16);
  }
  __syncthreads();
  #pragma unroll
  for (int ks=0; ks<16; ++ks){
    s16x8 av = *(const s16x8*)(ap0 + ks*32);
    s16x8 bp = *(const s16x8*)(cbrowP + ks*16);
    LPC = __builtin_amdgcn_mfma_f32_16x16x32_bf16(av, bp, LPC, 0, 0, 0);
  }
  if (lm < 8){
    const float* orow = out + ((size_t)(lm*TT + 0))*VV;
    int vb = vbase + lgp*4;
    #pragma unroll
    for (int r=0;r<4;++r){ int v = vb + r; Lh4[r] = (v < VV) ? orow[v] : 0.f; }
  }

  for (int t=0; t<TT; ++t){
    // ---- wait lse(t-1) ----
    if (t > 0){
      if (tid == 0){
        while (__hip_atomic_load(go, __ATOMIC_RELAXED, __HIP_MEMORY_SCOPE_AGENT) < (uint_t)t)
          __builtin_amdgcn_s_sleep(1);
      }
      __syncthreads();
      if (tid < 8)
        lseL[tid] = __hip_atomic_load((const float*)(ws + OFF_LSE + (t-1)*8 + tid),
                                      __ATOMIC_RELAXED, __HIP_MEMORY_SCOPE_AGENT);
    }
    __syncthreads();
    if (tid < 8){
      float pd = 0.f;
      if (t > 0)
        pd = qbufL[tid] + ws[OFF_HWV + (t-1)*8 + tid] + cst[1] - lseL[tid]*cst[2];
      gamL[tid] = sigm(pd + ws[OFF_WY + tid*TT + t] + ws[OFF_HS + t*8 + tid] + cst[0]);
    }
    __syncthreads();
    if (tid < 256){
      int b = tid >> 5, j = tid & 31;
      int row = t*8 + b;
      float gg = gamL[b];
      float p = ws[OFF_P + row*UU + j];
      float eu = suL[b][j];
      float mix = (1.f-gg)*p + gg*eu;
      float s2 = mix;
      #pragma unroll
      for (int off=16; off; off>>=1) s2 += __shfl_xor(s2, off);
      float su = mix / s2;
      suL[b][j] = su;
      if (j == 0) s2L[b] = s2;
      float qp = su * ws[OFF_E + row*UU + j];
      #pragma unroll
      for (int off=16; off; off>>=1) qp += __shfl_xor(qp, off);
      if (j == 0) qbufL[b] = qp;
    }
    __syncthreads();
    if (bid < 8 && tid < 32)
      out[SU_OFF + (bid*TT + t)*UU + tid] = suL[bid][tid];

    // ---- combine: logits = ((1-g)LPC + g LEC)/s2 + Lh ----
    {
      float pm = -1e30f, ps = 0.f;
      if (lm < 8){
        float gg = gamL[lm];
        float inv = 1.f / s2L[lm];
        float* orow = out + ((size_t)(lm*TT + t))*VV;
        int vb = vbase + lgp*4;
        float l4v[4];
        #pragma unroll
        for (int r=0;r<4;++r)
          l4v[r] = ((1.f-gg)*LPC[r] + gg*LEC[r])*inv + Lh4[r];
        if (vb + 3 < VV){
          *(float4*)(orow + vb) = make_float4(l4v[0],l4v[1],l4v[2],l4v[3]);
        } else {
          #pragma unroll
          for (int r=0;r<4;++r){
            int v = vb + r;
            if (v < VV) orow[v] = l4v[r]; else l4v[r] = -1e30f;
          }
        }
        #pragma unroll
        for (int i=0;i<4;++i) pm = fmaxf(pm, l4v[i]);
        #pragma unroll
        for (int i=0;i<4;++i) ps += (l4v[i] > -5e29f) ? __expf(l4v[i]-pm) : 0.f;
      }
      #pragma unroll
      for (int off=16; off<=32; off<<=1){
        float mo = __shfl_xor(pm, off);
        float so = __shfl_xor(ps, off);
        float nm = fmaxf(pm, mo);
        ps = ps*__expf(pm-nm) + so*__expf(mo-nm);
        pm = nm;
      }
      if (lgp == 0 && lm < 8) wred[wid][lm] = make_float2(pm, ps);
    }
    __syncthreads();
    if (tid < 8){
      float m = -1e30f, s = 0.f;
      #pragma unroll
      for (int w=0; w<8; ++w){
        float2 e = wred[w][tid];
        float nm = fmaxf(m, e.x);
        s = s*__expf(m-nm) + e.y*__expf(e.x-nm);
        m = nm;
      }
      *(float2*)(ws + OFF_PART + (t&1)*4096 + (bid*8 + tid)*2) = make_float2(m, s);
    }
    __syncthreads();
    if (tid == 0)
      __hip_atomic_store(&flags[bid*32], (uint_t)(t+1), __ATOMIC_RELEASE, __HIP_MEMORY_SCOPE_AGENT);

    // ---- slack: prepare t+1 (EC, cbPC, MFMAs, Lh preload) ----
    if (t < TT-1){
      int tn = t + 1;
      {
        int b = tid >> 6, l64 = tid & 63;
        int m8 = l64 * 8;
        int row = tn*8 + b;
        const ushort_t* Crow = (const ushort_t*)(ws + OFF_C) + ((size_t)row*UU)*512 + m8;
        float acc[8];
        #pragma unroll
        for (int i=0;i<8;++i) acc[i]=0.f;
        // fixed-bound unrolled u-loop: su[u]==0 for u>=u_len so extra terms are exact 0
        #pragma unroll 8
        for (int u=0; u<UU; ++u){
          float su = suL[b][u];
          uint4 c0 = *(const uint4*)(Crow + (size_t)u*512);
          uint_t cc[4] = {c0.x,c0.y,c0.z,c0.w};
          #pragma unroll
          for (int q=0;q<4;++q){
            acc[2*q]   += su * __uint_as_float((cc[q] & 0xffffu) << 16);
            acc[2*q+1] += su * __uint_as_float((cc[q] >> 16) << 16);
          }
        }
        #pragma unroll
        for (int q=0;q<4;++q)
          cbEC[b*260 + l64*4 + q] = (uint_t)to_bf16(acc[2*q]) | ((uint_t)to_bf16(acc[2*q+1]) << 16);
        const float* PCrow = ws + OFF_PC + (size_t)row*512 + m8;
        float4 p0 = *(const float4*)PCrow;
        float4 p1 = *(const float4*)(PCrow + 4);
        cbPC[b*260 + l64*4 + 0] = (uint_t)to_bf16(p0.x) | ((uint_t)to_bf16(p0.y) << 16);
        cbPC[b*260 + l64*4 + 1] = (uint_t)to_bf16(p0.z) | ((uint_t)to_bf16(p0.w) << 16);
        cbPC[b*260 + l64*4 + 2] = (uint_t)to_bf16(p1.x) | ((uint_t)to_bf16(p1.y) << 16);
        cbPC[b*260 + l64*4 + 3] = (uint_t)to_bf16(p1.z) | ((uint_t)to_bf16(p1.w) << 16);
      }
      __syncthreads();
      LPC = (f32x4){0.f,0.f,0.f,0.f};
      LEC = (f32x4){0.f,0.f,0.f,0.f};
      #pragma unroll
      for (int ks=0; ks<16; ++ks){
        s16x8 av = *(const s16x8*)(ap0 + ks*32);
        s16x8 bp = *(const s16x8*)(cbrowP + ks*16);
        s16x8 be = *(const s16x8*)(cbrowE + ks*16);
        LPC = __builtin_amdgcn_mfma_f32_16x16x32_bf16(av, bp, LPC, 0, 0, 0);
        LEC = __builtin_amdgcn_mfma_f32_16x16x32_bf16(av, be, LEC, 0, 0, 0);
      }
      if (lm < 8){
        const float* orow = out + ((size_t)(lm*TT + tn))*VV;
        int vb = vbase + lgp*4;
        #pragma unroll
        for (int r=0;r<4;++r){ int v = vb + r; Lh4[r] = (v < VV) ? orow[v] : 0.f; }
      }
    }
  }
}

// ---------------- finals ----------------

__global__ void k_sub2(const float* __restrict__ ws, float* __restrict__ out){
  int v = blockIdx.x*256 + threadIdx.x;
  int tb = blockIdx.y;
  int t = tb >> 3, b = tb & 7;
  if (v < VV) out[(size_t)(b*TT+t)*VV + v] -= ws[OFF_LSE + tb];
}

__global__ void k_suw2(const int* __restrict__ word2utt, const float* __restrict__ ws,
                       float* __restrict__ out){
  int row = blockIdx.x;   // t*8+b
  int t = row >> 3, b = row & 7;
  int tid = threadIdx.x;
  for (int w=tid; w<WW; w+=256){
    int seg = word2utt[b*WW + w];
    float su = out[SU_OFF + (b*TT+t)*UU + seg];
    float pw = ws[OFF_SW + row*WW + w];
    out[SUW_OFF + (b*TT+t)*WW + w] = su*pw;
  }
}

extern "C" void kernel_launch(void* const* d_in, const int* in_sizes, int n_in,
                              void* d_out, int out_size, void* d_ws, size_t ws_size,
                              hipStream_t stream) {
  const int*   target   = (const int*)d_in[0];
  const float* u_output = (const float*)d_in[1];
  const float* w_output = (const float*)d_in[2];
  const int*   u_len    = (const int*)d_in[3];
  const int*   w_len    = (const int*)d_in[4];
  const int*   word2utt = (const int*)d_in[5];
  const float* emb      = (const float*)d_in[6];
  const float* W_ih     = (const float*)d_in[7];
  const float* W_hh     = (const float*)d_in[8];
  const float* b_ih     = (const float*)d_in[9];
  const float* b_hh     = (const float*)d_in[10];
  const float* Wu       = (const float*)d_in[11];
  const float* Ww       = (const float*)d_in[13];
  const float* Wo       = (const float*)d_in[15];
  const float* bo       = (const float*)d_in[16];
  const float* Wd       = (const float*)d_in[17];
  const float* Wy       = (const float*)d_in[18];
  const float* Ws       = (const float*)d_in[19];
  const float* bs       = (const float*)d_in[20];
  float* out = (float*)d_out;
  float* ws  = (float*)d_ws;
  ushort_t* wov = (ushort_t*)(ws + OFF_WOV);
  ushort_t* hbt = (ushort_t*)(ws + OFF_HBT);

  // --- reset barrier flags (per launch, graph-replay safe) ---
  hipMemsetAsync(ws + OFF_SYNC, 0, 16384*sizeof(float), stream);

  // --- batched precompute ---
  hipLaunchKernelGGL(k_y, dim3(512), dim3(256), 0, stream, target, emb, Wy, ws);
  hipLaunchKernelGGL((k_gemm_b<1>), dim3(24,8,1), dim3(256), 0, stream,
                     ws+OFF_YALL, 256, 0, W_ih, 256, 0, b_ih, ws+OFF_GI, 1536, 0, 256);
  hipLaunchKernelGGL(k_h0, dim3(16), dim3(256), 0, stream, u_output, u_len, ws);
  hipLaunchKernelGGL(k_wovc, dim3(7520), dim3(256), 0, stream, Wo, wov);
  hipMemsetAsync(ws + OFF_WV, 0, 1536*sizeof(float), stream);
  hipLaunchKernelGGL(k_wv, dim3(235), dim3(256), 0, stream, Wo, bo, Wd, ws+OFF_WV);

  // --- GRU hidden chain: persistent, split-K, single-hop barrier (+hbt tail) ---
  hipLaunchKernelGGL(k_gru_persist, dim3(NBG), dim3(1024), 0, stream, W_hh, b_hh, ws);

  // --- batched post-h precompute ---
  hipLaunchKernelGGL(k_lh_mfma, dim3(235, 4), dim3(256), 0, stream, Wo, bo, hbt, out);
  hipLaunchKernelGGL((k_gemm_b<0>), dim3(8,8,1), dim3(256), 0, stream,
                     ws+OFF_HALL, 512, 0, Wu, 512, 0, (const float*)nullptr, ws+OFF_HU, 512, 0, 512);
  hipLaunchKernelGGL((k_gemm_b<0>), dim3(8,8,1), dim3(256), 0, stream,
                     ws+OFF_HALL, 512, 0, Ww, 512, 0, (const float*)nullptr, ws+OFF_HW, 512, 0, 512);
  hipLaunchKernelGGL(k_hdots, dim3(256), dim3(256), 0, stream, Ws, ws);
  hipLaunchKernelGGL(k_p, dim3(512), dim3(256), 0, stream, u_output, u_len, ws);
  hipLaunchKernelGGL((k_gemm_b<1>), dim3(8,1,8), dim3(256), 0, stream,
                     ws+OFF_HW, 4096, 512, w_output, 512, 262144, (const float*)nullptr,
                     ws+OFF_SW, 4096, 512, 512);
  hipLaunchKernelGGL(k_pw, dim3(512), dim3(256), 0, stream, word2utt, w_len, ws);
  hipLaunchKernelGGL(k_C, dim3(512), dim3(256), 0, stream,
                     w_output, w_len, u_len, word2utt, ws);

  // --- serial decode: 235 workers + 1 leader, pipelined MFMA ---
  hipLaunchKernelGGL(k_decode_persist, dim3(NDB+1), dim3(512), 0, stream,
                     u_len, bs, wov, ws, out);

  // --- batched finals ---
  hipLaunchKernelGGL(k_sub2, dim3(118, 512), dim3(256), 0, stream, ws, out);
  hipLaunchKernelGGL(k_suw2, dim3(512), dim3(256), 0, stream, word2utt, ws, out);
}

// Round 14
// 1884.596 us; speedup vs baseline: 1.1872x; 1.1872x over previous
//
#include <hip/hip_runtime.h>
#include <math.h>

typedef unsigned short ushort_t;
typedef unsigned int uint_t;
typedef unsigned long long ulong_t;
typedef __attribute__((ext_vector_type(8))) short s16x8;
typedef __attribute__((ext_vector_type(4))) float f32x4;

#define BB 8
#define TT 64
#define VV 30000
#define VP 30080
#define EE 256
#define HH 512
#define MM 512
#define UU 32
#define WW 512
#define G3 1536
#define NDB 235
#define NBG 64

// workspace offsets (floats)
#define OFF_GI    0          // 512*1536
#define OFF_YALL  786432     // 512*256
#define OFF_WY    917504     // 512
#define OFF_H0    918016     // 4096
#define OFF_HALL  922112     // 512*512
#define OFF_HU    1184256    // 512*512
#define OFF_HW    1446400    // 512*512
#define OFF_HS    1708544    // 512
#define OFF_HWV   1709056    // 512
#define OFF_P     1709568    // 64*8*32
#define OFF_SW    1725952    // 64*8*512  (sw -> pw in place)
#define OFF_C     1988096    // bf16 64*8*32*512 = 4194304 float slots
#define OFF_E     6182400    // 16384
#define OFF_WV    6198784    // 1024 + 2, pad 1536
#define OFF_PART  6200320    // double buffer 2*4096
#define OFF_LSE   6208512    // 512
#define OFF_WOV   6209024    // bf16 [v][k] 30080*512 = 7700480 float slots
#define OFF_HBT   13909504   // bf16 512*512 = 131072 float slots
#define OFF_SYNC  14040576   // 16384 floats (uint view): gru flags @0 (blk*32),
                             //   dec flags @8192+blk*32, dec go @16000
#define OFF_PC    14056960   // fp32 512 rows x 512 m = 262144
// total 14319104 floats = 57.3 MB

#define DEC_SZ (BB*TT*VV)
#define SUW_OFF DEC_SZ
#define SU_OFF  (DEC_SZ + BB*TT*WW)

__device__ __forceinline__ float sigm(float x){ return 1.0f/(1.0f+__expf(-x)); }
__device__ __forceinline__ ushort_t to_bf16(float f){
  uint_t u = __float_as_uint(f);
  return (ushort_t)((u + 0x7fffu + ((u>>16)&1u)) >> 16);
}

// ---------------- precompute ----------------

template<int TRANSB>
__global__ void __launch_bounds__(256)
k_gemm_b(const float* __restrict__ A, int lda, int aS,
         const float* __restrict__ B, int ldb, int bS,
         const float* __restrict__ bias,
         float* __restrict__ C, int ldc, int cS, int K){
  A += (size_t)blockIdx.z * aS;
  B += (size_t)blockIdx.z * bS;
  C += (size_t)blockIdx.z * cS;
  __shared__ float As[32][65];
  __shared__ float Bs[32][65];
  int tid = threadIdx.x;
  int bx = blockIdx.x, by = blockIdx.y;
  int tx = tid & 15, ty = tid >> 4;
  float acc[4][4] = {};
  for (int k0 = 0; k0 < K; k0 += 32){
    {
      int r = tid >> 2, cbase = (tid & 3) * 8;
      const float* ap = A + (size_t)(by*64 + r)*lda + k0 + cbase;
      #pragma unroll
      for (int i=0;i<8;++i) As[cbase+i][r] = ap[i];
    }
    if (TRANSB){
      int r = tid >> 2, cbase = (tid & 3) * 8;
      const float* bp = B + (size_t)(bx*64 + r)*ldb + k0 + cbase;
      #pragma unroll
      for (int i=0;i<8;++i) Bs[cbase+i][r] = bp[i];
    } else {
      int kk = tid >> 3, cbase = (tid & 7) * 8;
      const float* bp = B + (size_t)(k0 + kk)*ldb + bx*64 + cbase;
      #pragma unroll
      for (int i=0;i<8;++i) Bs[kk][cbase+i] = bp[i];
    }
    __syncthreads();
    #pragma unroll
    for (int kk=0;kk<32;++kk){
      float a0=As[kk][ty*4+0], a1=As[kk][ty*4+1], a2=As[kk][ty*4+2], a3=As[kk][ty*4+3];
      float b0=Bs[kk][tx*4+0], b1=Bs[kk][tx*4+1], b2=Bs[kk][tx*4+2], b3=Bs[kk][tx*4+3];
      acc[0][0]+=a0*b0; acc[0][1]+=a0*b1; acc[0][2]+=a0*b2; acc[0][3]+=a0*b3;
      acc[1][0]+=a1*b0; acc[1][1]+=a1*b1; acc[1][2]+=a1*b2; acc[1][3]+=a1*b3;
      acc[2][0]+=a2*b0; acc[2][1]+=a2*b1; acc[2][2]+=a2*b2; acc[2][3]+=a2*b3;
      acc[3][0]+=a3*b0; acc[3][1]+=a3*b1; acc[3][2]+=a3*b2; acc[3][3]+=a3*b3;
    }
    __syncthreads();
  }
  #pragma unroll
  for (int i=0;i<4;++i){
    int row = by*64 + ty*4 + i;
    #pragma unroll
    for (int j=0;j<4;++j){
      int col = bx*64 + tx*4 + j;
      float v = acc[i][j];
      if (bias) v += bias[col];
      C[(size_t)row*ldc + col] = v;
    }
  }
}

// gather y + wy dot, one block per bt row
__global__ void k_y(const int* __restrict__ target, const float* __restrict__ emb,
                    const float* __restrict__ Wy, float* __restrict__ ws){
  int bt = blockIdx.x;
  int e = threadIdx.x;            // 256 = EE
  __shared__ float r[256];
  int tok = target[bt];
  float v = emb[tok*EE + e];
  ws[OFF_YALL + bt*EE + e] = v;
  r[e] = v * Wy[e];
  __syncthreads();
  for (int s=128; s; s>>=1){ if (e<s) r[e]+=r[e+s]; __syncthreads(); }
  if (e == 0) ws[OFF_WY + bt] = r[0];
}

__global__ void k_h0(const float* __restrict__ u_output, const int* __restrict__ u_len,
                     float* __restrict__ ws){
  int idx = blockIdx.x*256 + threadIdx.x;   // B*H
  int b = idx >> 9; int k = idx & 511;
  int u = u_len[b]-1;
  ws[OFF_H0 + idx] = u_output[(b*UU+u)*MM + k];
}

// WOV[v][k] = bf16(Wo[v][k]) for k<512 (ctx half); rows v>=VV zero. VP rows.
__global__ void __launch_bounds__(256)
k_wovc(const float* __restrict__ Wo, ushort_t* __restrict__ wov){
  int idx8 = blockIdx.x*256 + threadIdx.x;   // VP*512/8 items of 8 elems
  int v = idx8 >> 6;
  int k8 = (idx8 & 63) << 3;
  uint_t u0=0,u1=0,u2=0,u3=0;
  if (v < VV){
    const float* src = Wo + (size_t)v*1024 + k8;
    float4 f0 = *(const float4*)src;
    float4 f1 = *(const float4*)(src+4);
    u0 = (uint_t)to_bf16(f0.x) | ((uint_t)to_bf16(f0.y) << 16);
    u1 = (uint_t)to_bf16(f0.z) | ((uint_t)to_bf16(f0.w) << 16);
    u2 = (uint_t)to_bf16(f1.x) | ((uint_t)to_bf16(f1.y) << 16);
    u3 = (uint_t)to_bf16(f1.z) | ((uint_t)to_bf16(f1.w) << 16);
  }
  uint4 pk = make_uint4(u0,u1,u2,u3);
  *(uint4*)(wov + (size_t)idx8*8) = pk;
}

// wv[k] = sum_v Wo[v][k]*Wd[v]; wv[1024]=bo.Wd; wv[1025]=sum Wd
__global__ void __launch_bounds__(256)
k_wv(const float* __restrict__ Wo, const float* __restrict__ bo,
     const float* __restrict__ Wd, float* __restrict__ wv){
  __shared__ float wds[128];
  __shared__ float red[256];
  int tid = threadIdx.x;
  int v0 = blockIdx.x*128;
  float pbo=0.f, pwd=0.f;
  if (tid < 128){
    int v = v0 + tid;
    float wd = (v<VV)? Wd[v] : 0.f;
    wds[tid] = wd;
    pbo = wd * ((v<VV)? bo[v] : 0.f);
    pwd = wd;
  }
  __syncthreads();
  float4 acc = {0,0,0,0};
  int nmax = (v0 + 128 <= VV) ? 128 : (VV - v0);
  for (int i=0;i<nmax;++i){
    float wd = wds[i];
    float4 w4 = *(const float4*)(Wo + (size_t)(v0+i)*1024 + tid*4);
    acc.x += wd*w4.x; acc.y += wd*w4.y; acc.z += wd*w4.z; acc.w += wd*w4.w;
  }
  atomicAdd(&wv[tid*4+0], acc.x);
  atomicAdd(&wv[tid*4+1], acc.y);
  atomicAdd(&wv[tid*4+2], acc.z);
  atomicAdd(&wv[tid*4+3], acc.w);
  red[tid] = pbo; __syncthreads();
  for (int s=128; s; s>>=1){ if (tid<s) red[tid]+=red[tid+s]; __syncthreads(); }
  if (tid==0) atomicAdd(&wv[1024], red[0]);
  __syncthreads();
  red[tid] = pwd; __syncthreads();
  for (int s=128; s; s>>=1){ if (tid<s) red[tid]+=red[tid+s]; __syncthreads(); }
  if (tid==0) atomicAdd(&wv[1025], red[0]);
}

// ---------------- persistent GRU chain (64 x 1024, split-K, single-hop) ----------------

__global__ void __launch_bounds__(1024)
k_gru_persist(const float* __restrict__ W_hh, const float* __restrict__ b_hh,
              float* __restrict__ ws){
  uint_t* flags = (uint_t*)(ws + OFF_SYNC);
  int tid  = threadIdx.x;
  int wid  = tid >> 6;          // 0..15
  int lane = tid & 63;
  int half = wid >> 3;          // 0/1: K-half
  int kl   = wid & 7;           // k-local 0..7
  int k    = blockIdx.x*8 + kl; // 0..511
  const float* gi_all = ws + OFF_GI;
  const float* wr = W_hh + (size_t)k*HH;
  const float* wz = W_hh + (size_t)(HH+k)*HH;
  const float* wn = W_hh + (size_t)(2*HH+k)*HH;
  __shared__ float red[16][24];

  for (int t=0; t<TT; ++t){
    const float* hin = (t==0) ? (ws+OFF_H0) : (ws+OFF_HALL + (size_t)(t-1)*4096);
    float* hout = ws + OFF_HALL + (size_t)t*4096;
    float pr[8], pz[8], pn[8];
    #pragma unroll
    for (int b=0;b<8;++b){ pr[b]=0.f; pz[b]=0.f; pn[b]=0.f; }
    int kk0 = half*256 + lane;
    #pragma unroll
    for (int it=0; it<4; ++it){
      int kk = kk0 + it*64;
      float w1 = wr[kk], w2 = wz[kk], w3 = wn[kk];
      #pragma unroll
      for (int b=0;b<8;++b){
        float hv = hin[b*HH+kk];
        pr[b] += hv*w1; pz[b] += hv*w2; pn[b] += hv*w3;
      }
    }
    #pragma unroll
    for (int off=32; off; off>>=1){
      #pragma unroll
      for (int b=0;b<8;++b){
        pr[b] += __shfl_xor(pr[b],off);
        pz[b] += __shfl_xor(pz[b],off);
        pn[b] += __shfl_xor(pn[b],off);
      }
    }
    if (lane == 0){
      #pragma unroll
      for (int b=0;b<8;++b){
        red[wid][b]    = pr[b];
        red[wid][8+b]  = pz[b];
        red[wid][16+b] = pn[b];
      }
    }
    __syncthreads();
    if (tid < 64){
      int klx = tid >> 3, b = tid & 7;
      int k2 = blockIdx.x*8 + klx;
      float prs = red[klx][b]    + red[8+klx][b];
      float pzs = red[klx][8+b]  + red[8+klx][8+b];
      float pns = red[klx][16+b] + red[8+klx][16+b];
      const float* gi = gi_all + (b*TT + t)*G3;
      float r = sigm(gi[k2]      + prs + b_hh[k2]);
      float z = sigm(gi[HH+k2]   + pzs + b_hh[HH+k2]);
      float n = tanhf(gi[2*HH+k2] + r*(pns + b_hh[2*HH+k2]));
      hout[b*HH+k2] = (1.f-z)*n + z*hin[b*HH+k2];
    }
    // single-hop poll-all barrier
    __syncthreads();
    if (tid == 0)
      __hip_atomic_store(&flags[blockIdx.x*32], (uint_t)(t+1), __ATOMIC_RELEASE, __HIP_MEMORY_SCOPE_AGENT);
    if (tid < NBG){
      while (__hip_atomic_load(&flags[tid*32], __ATOMIC_RELAXED, __HIP_MEMORY_SCOPE_AGENT) < (uint_t)(t+1))
        __builtin_amdgcn_s_sleep(1);
    }
    __syncthreads();
  }
  // tail: write hbt (bf16 of HALL)
  {
    ushort_t* hbt = (ushort_t*)(ws + OFF_HBT);
    int base = (blockIdx.x*1024 + tid)*4;
    #pragma unroll
    for (int i=0;i<4;++i) hbt[base+i] = to_bf16(ws[OFF_HALL + base + i]);
  }
}

// ---------------- h-half logits via MFMA ----------------

__global__ void __launch_bounds__(256)
k_lh_mfma(const float* __restrict__ Wo, const float* __restrict__ bo,
          const ushort_t* __restrict__ hbt, float* __restrict__ out){
  int tid = threadIdx.x;
  int wv = tid >> 6, l = tid & 63;
  int lm = l & 15, lg = l >> 4;
  int vbase = blockIdx.x*128 + wv*32;   // 2 v-subtiles of 16
  int rbase = blockIdx.y*128;           // 8 row-subtiles of 16
  f32x4 acc[2][8];
  #pragma unroll
  for (int s=0;s<2;++s)
    #pragma unroll
    for (int rt=0;rt<8;++rt) acc[s][rt] = (f32x4){0.f,0.f,0.f,0.f};

  for (int k0 = 0; k0 < 512; k0 += 32){
    int kk = k0 + lg*8;
    union { uint_t u[4]; s16x8 s; } af[2];
    #pragma unroll
    for (int s=0;s<2;++s){
      int v = vbase + s*16 + lm; if (v >= VV) v = VV-1;
      const float* ap = Wo + (size_t)v*1024 + 512 + kk;
      float4 f0 = *(const float4*)ap;
      float4 f1 = *(const float4*)(ap+4);
      af[s].u[0] = ((__float_as_uint(f0.x)+0x8000u)>>16) | ((__float_as_uint(f0.y)+0x8000u) & 0xffff0000u);
      af[s].u[1] = ((__float_as_uint(f0.z)+0x8000u)>>16) | ((__float_as_uint(f0.w)+0x8000u) & 0xffff0000u);
      af[s].u[2] = ((__float_as_uint(f1.x)+0x8000u)>>16) | ((__float_as_uint(f1.y)+0x8000u) & 0xffff0000u);
      af[s].u[3] = ((__float_as_uint(f1.z)+0x8000u)>>16) | ((__float_as_uint(f1.w)+0x8000u) & 0xffff0000u);
    }
    #pragma unroll
    for (int rt=0;rt<8;++rt){
      const ushort_t* bp = hbt + (size_t)(rbase + rt*16 + lm)*HH + kk;
      s16x8 bf = *(const s16x8*)bp;
      acc[0][rt] = __builtin_amdgcn_mfma_f32_16x16x32_bf16(af[0].s, bf, acc[0][rt], 0, 0, 0);
      acc[1][rt] = __builtin_amdgcn_mfma_f32_16x16x32_bf16(af[1].s, bf, acc[1][rt], 0, 0, 0);
    }
  }
  float bv[2][4];
  #pragma unroll
  for (int s=0;s<2;++s)
    #pragma unroll
    for (int r=0;r<4;++r){
      int v = vbase + s*16 + lg*4 + r;
      bv[s][r] = (v < VV) ? bo[v] : 0.f;
    }
  #pragma unroll
  for (int rt=0;rt<8;++rt){
    int row = rbase + rt*16 + lm;
    float* orow = out + (size_t)((row&7)*TT + (row>>3))*VV;
    #pragma unroll
    for (int s=0;s<2;++s){
      #pragma unroll
      for (int r=0;r<4;++r){
        int v = vbase + s*16 + lg*4 + r;
        if (v < VV) orow[v] = acc[s][rt][r] + bv[s][r];
      }
    }
  }
}

// ---------------- batched post-h ----------------

__global__ void k_hdots(const float* __restrict__ Ws, float* __restrict__ ws){
  int wid  = blockIdx.x*4 + (threadIdx.x>>6);  // 1024 waves
  int lane = threadIdx.x & 63;
  int row = wid >> 1, which = wid & 1;
  const float* h = ws + OFF_HALL + row*HH;
  const float* src = which ? (ws + OFF_WV + 512) : Ws;
  float acc = 0.f;
  for (int k=lane; k<HH; k+=64) acc += h[k]*src[k];
  for (int off=32; off; off>>=1) acc += __shfl_xor(acc, off);
  if (lane == 0) (which ? ws+OFF_HWV : ws+OFF_HS)[row] = acc;
}

__global__ void k_p(const float* __restrict__ u_output, const int* __restrict__ u_len,
                    float* __restrict__ ws){
  int row = blockIdx.x;          // t*8+b
  int b = row & 7;
  int tid = threadIdx.x;
  __shared__ float su_s[UU];
  {
    int u = tid >> 3, l8 = tid & 7;
    const float* hu = ws + OFF_HU + row*512;
    const float* uo = u_output + (size_t)(b*UU + u)*MM;
    float acc = 0.f;
    for (int m=l8; m<MM; m+=8) acc += hu[m]*uo[m];
    acc += __shfl_xor(acc,1); acc += __shfl_xor(acc,2); acc += __shfl_xor(acc,4);
    if (l8 == 0) su_s[u] = acc;
  }
  __syncthreads();
  if (tid < 32){
    int ul = u_len[b];
    float sv = su_s[tid];
    bool valid = tid < ul;
    float mv = valid ? sv : -1e30f;
    for (int off=16; off; off>>=1) mv = fmaxf(mv, __shfl_xor(mv, off));
    float e = valid ? __expf(sv - mv) : 0.f;
    float ssum = e;
    for (int off=16; off; off>>=1) ssum += __shfl_xor(ssum, off);
    ws[OFF_P + row*UU + tid] = e/ssum;
  }
}

__global__ void k_pw(const int* __restrict__ word2utt, const int* __restrict__ w_len,
                     float* __restrict__ ws){
  int row = blockIdx.x;  // t*8+b
  int b = row & 7;
  int tid = threadIdx.x;
  __shared__ float sarr[WW];
  __shared__ int   seg[WW];
  __shared__ float marr[UU], darr[UU];
  int wl = w_len[b];
  float* swrow = ws + OFF_SW + row*WW;
  for (int w=tid; w<WW; w+=256){ sarr[w] = swrow[w]; seg[w] = word2utt[b*WW+w]; }
  __syncthreads();
  {
    int g = tid>>3, l8 = tid&7;
    float mv = -1e30f;
    for (int w=l8; w<wl; w+=8) if (seg[w]==g) mv = fmaxf(mv, sarr[w]);
    mv = fmaxf(mv, __shfl_xor(mv,1)); mv = fmaxf(mv, __shfl_xor(mv,2)); mv = fmaxf(mv, __shfl_xor(mv,4));
    float d = 0.f;
    for (int w=l8; w<wl; w+=8) if (seg[w]==g) d += __expf(sarr[w]-mv);
    d += __shfl_xor(d,1); d += __shfl_xor(d,2); d += __shfl_xor(d,4);
    if (l8 == 0){ marr[g]=mv; darr[g]=d; }
  }
  __syncthreads();
  for (int w=tid; w<WW; w+=256){
    float val = 0.f;
    if (w < wl){ int u = seg[w]; val = __expf(sarr[w]-marr[u])/darr[u]; }
    swrow[w] = val;
  }
}

// C (bf16), E, and PC = p . C  (PC folded in)
__global__ void __launch_bounds__(256)
k_C(const float* __restrict__ w_output, const int* __restrict__ w_len,
    const int* __restrict__ u_len, const int* __restrict__ word2utt,
    float* __restrict__ ws){
  int row = blockIdx.x;  // t*8+b
  int b = row & 7;
  int tid = threadIdx.x;
  __shared__ float pws[WW];
  __shared__ int   seg[WW];
  __shared__ int   st[UU], en[UU];
  __shared__ float wvs[512];
  __shared__ float parr[UU];
  __shared__ float red32[UU][4];
  int wl = w_len[b], ul = u_len[b];
  const float* pwrow = ws + OFF_SW + row*WW;
  for (int w=tid; w<WW; w+=256){ pws[w] = pwrow[w]; seg[w] = word2utt[b*WW+w]; }
  for (int m=tid; m<512; m+=256) wvs[m] = ws[OFF_WV + m];
  if (tid < UU){ st[tid]=0; en[tid]=0; parr[tid] = ws[OFF_P + row*UU + tid]; }
  __syncthreads();
  for (int w=tid; w<wl; w+=256){
    int s = seg[w];
    if (w==0 || seg[w-1]!=s) st[s]=w;
    if (w==wl-1 || seg[w+1]!=s) en[s]=w+1;
  }
  __syncthreads();
  ushort_t* Cu = (ushort_t*)(ws + OFF_C);
  int m0 = tid, m1 = tid + 256;
  int lane = tid & 63, wvi = tid >> 6;
  float pc0 = 0.f, pc1 = 0.f;
  for (int u=0; u<UU; ++u){
    float acc0=0.f, acc1=0.f;
    if (u < ul){
      int s = st[u], e = en[u];
      for (int w=s; w<e; ++w){
        float p = pws[w];
        const float* wo = w_output + ((size_t)(b*WW+w))*MM;
        acc0 += p*wo[m0];
        acc1 += p*wo[m1];
      }
    }
    size_t cbase = ((size_t)row*UU + u)*512;
    Cu[cbase + m0] = to_bf16(acc0);
    Cu[cbase + m1] = to_bf16(acc1);
    float pu = parr[u];
    pc0 += pu*acc0; pc1 += pu*acc1;
    float part = acc0*wvs[m0] + acc1*wvs[m1];
    #pragma unroll
    for (int off=32; off; off>>=1) part += __shfl_xor(part, off);
    if (lane == 0) red32[u][wvi] = part;
  }
  ws[OFF_PC + (size_t)row*512 + m0] = pc0;
  ws[OFF_PC + (size_t)row*512 + m1] = pc1;
  __syncthreads();
  if (tid < UU)
    ws[OFF_E + row*UU + tid] = red32[tid][0]+red32[tid][1]+red32[tid][2]+red32[tid][3];
}

// -------- persistent decode: 235 workers + 1 leader; pipelined MFMA --------

__global__ void __launch_bounds__(512)
k_decode_persist(const int* __restrict__ u_len, const float* __restrict__ bs,
                 const ushort_t* __restrict__ wov,
                 float* __restrict__ ws, float* __restrict__ out){
  int bid = blockIdx.x;
  int tid = threadIdx.x;
  uint_t* sy    = (uint_t*)(ws + OFF_SYNC);
  uint_t* flags = sy + 8192;
  uint_t* go    = sy + 16000;

  // ---------- leader block ----------
  if (bid == NDB){
    int wid = tid >> 6, l = tid & 63;   // wid = b
    for (int t=0; t<TT; ++t){
      if (tid < NDB){
        while (__hip_atomic_load(&flags[tid*32], __ATOMIC_RELAXED, __HIP_MEMORY_SCOPE_AGENT) < (uint_t)(t+1))
          __builtin_amdgcn_s_sleep(1);
      }
      __syncthreads();
      {
        const ulong_t* partq = (const ulong_t*)(ws + OFF_PART + (t&1)*4096);
        float ma = -1e30f, sa = 0.f;
        #pragma unroll
        for (int it=0; it<4; ++it){
          int i = l + it*64;
          if (i < NDB){
            ulong_t pq = __hip_atomic_load(&partq[i*8 + wid], __ATOMIC_RELAXED, __HIP_MEMORY_SCOPE_AGENT);
            float m = __uint_as_float((uint_t)pq);
            float s = __uint_as_float((uint_t)(pq >> 32));
            float mm = fmaxf(ma, m);
            sa = sa*__expf(ma-mm) + s*__expf(m-mm);
            ma = mm;
          }
        }
        #pragma unroll
        for (int off=32; off; off>>=1){
          float mo = __shfl_xor(ma, off);
          float so = __shfl_xor(sa, off);
          float mm = fmaxf(ma, mo);
          sa = sa*__expf(ma-mm) + so*__expf(mo-mm);
          ma = mm;
        }
        if (l == 0)
          __hip_atomic_store((float*)(ws + OFF_LSE + t*8 + wid), ma + logf(sa),
                             __ATOMIC_RELAXED, __HIP_MEMORY_SCOPE_AGENT);
      }
      __syncthreads();
      if (tid == 0)
        __hip_atomic_store(go, (uint_t)(t+1), __ATOMIC_RELEASE, __HIP_MEMORY_SCOPE_AGENT);
    }
    return;
  }

  // ---------- worker ----------
  __shared__ float suL[8][32];
  __shared__ float qbufL[8], lseL[8], gamL[8], s2L[8];
  __shared__ int   ulS[8];
  __shared__ uint_t cbPC[16*260];
  __shared__ uint_t cbEC[16*260];
  __shared__ float2 wred[8][8];
  __shared__ float cst[4];
  if (tid == 0){ cst[0]=bs[0]; cst[1]=ws[OFF_WV+1024]; cst[2]=ws[OFF_WV+1025]; }
  if (tid < 8){ qbufL[tid]=0.f; lseL[tid]=0.f; s2L[tid]=1.f; ulS[tid]=u_len[tid]; }
  if (tid < 256) suL[tid>>5][tid&31] = 0.f;
  for (int i=tid; i<8*260; i+=512){ cbPC[8*260 + i] = 0u; cbEC[8*260 + i] = 0u; }
  __syncthreads();

  int wid = tid >> 6, l = tid & 63;
  int lm = l & 15, lgp = l >> 4;
  int vbase = bid*128 + wid*16;
  const ushort_t* ap0 = wov + (size_t)(vbase + lm)*512 + lgp*8;
  const uint_t* cbrowP = cbPC + lm*260 + lgp*4;
  const uint_t* cbrowE = cbEC + lm*260 + lgp*4;

  f32x4 LPC = {0.f,0.f,0.f,0.f};
  f32x4 LEC = {0.f,0.f,0.f,0.f};
  float Lh4[4] = {0.f,0.f,0.f,0.f};

  // prologue: cbPC(0) from PC row 0; LEC(0)=0; MFMA LPC(0); preload Lh(0)
  {
    int b = tid >> 6, l64 = tid & 63;
    const float* PCrow = ws + OFF_PC + (size_t)(b)*512 + l64*8;
    float4 p0 = *(const float4*)PCrow;
    float4 p1 = *(const float4*)(PCrow + 4);
    cbPC[b*260 + l64*4 + 0] = (uint_t)to_bf16(p0.x) | ((uint_t)to_bf16(p0.y) << 16);
    cbPC[b*260 + l64*4 + 1] = (uint_t)to_bf16(p0.z) | ((uint_t)to_bf16(p0.w) << 16);
    cbPC[b*260 + l64*4 + 2] = (uint_t)to_bf16(p1.x) | ((uint_t)to_bf16(p1.y) << 16);
    cbPC[b*260 + l64*4 + 3] = (uint_t)to_bf16(p1.z) | ((uint_t)to_bf16(p1.w) << 16);
  }
  __syncthreads();
  #pragma unroll
  for (int ks=0; ks<16; ++ks){
    s16x8 av = *(const s16x8*)(ap0 + ks*32);
    s16x8 bp = *(const s16x8*)(cbrowP + ks*16);
    LPC = __builtin_amdgcn_mfma_f32_16x16x32_bf16(av, bp, LPC, 0, 0, 0);
  }
  if (lm < 8){
    const float* orow = out + ((size_t)(lm*TT + 0))*VV;
    int vb = vbase + lgp*4;
    #pragma unroll
    for (int r=0;r<4;++r){ int v = vb + r; Lh4[r] = (v < VV) ? orow[v] : 0.f; }
  }

  for (int t=0; t<TT; ++t){
    // ---- wait lse(t-1) ----
    if (t > 0){
      if (tid == 0){
        while (__hip_atomic_load(go, __ATOMIC_RELAXED, __HIP_MEMORY_SCOPE_AGENT) < (uint_t)t)
          __builtin_amdgcn_s_sleep(1);
      }
      __syncthreads();
      if (tid < 8)
        lseL[tid] = __hip_atomic_load((const float*)(ws + OFF_LSE + (t-1)*8 + tid),
                                      __ATOMIC_RELAXED, __HIP_MEMORY_SCOPE_AGENT);
    }
    __syncthreads();
    if (tid < 8){
      float pd = 0.f;
      if (t > 0)
        pd = qbufL[tid] + ws[OFF_HWV + (t-1)*8 + tid] + cst[1] - lseL[tid]*cst[2];
      gamL[tid] = sigm(pd + ws[OFF_WY + tid*TT + t] + ws[OFF_HS + t*8 + tid] + cst[0]);
    }
    __syncthreads();
    if (tid < 256){
      int b = tid >> 5, j = tid & 31;
      int row = t*8 + b;
      float gg = gamL[b];
      float p = ws[OFF_P + row*UU + j];
      float eu = suL[b][j];
      float mix = (1.f-gg)*p + gg*eu;
      float s2 = mix;
      #pragma unroll
      for (int off=16; off; off>>=1) s2 += __shfl_xor(s2, off);
      float su = mix / s2;
      suL[b][j] = su;
      if (j == 0) s2L[b] = s2;
      float qp = su * ws[OFF_E + row*UU + j];
      #pragma unroll
      for (int off=16; off; off>>=1) qp += __shfl_xor(qp, off);
      if (j == 0) qbufL[b] = qp;
    }
    __syncthreads();
    if (bid < 8 && tid < 32)
      out[SU_OFF + (bid*TT + t)*UU + tid] = suL[bid][tid];

    // ---- combine: logits = ((1-g)LPC + g LEC)/s2 + Lh ----
    {
      float pm = -1e30f, ps = 0.f;
      if (lm < 8){
        float gg = gamL[lm];
        float inv = 1.f / s2L[lm];
        float* orow = out + ((size_t)(lm*TT + t))*VV;
        int vb = vbase + lgp*4;
        float l4v[4];
        #pragma unroll
        for (int r=0;r<4;++r)
          l4v[r] = ((1.f-gg)*LPC[r] + gg*LEC[r])*inv + Lh4[r];
        if (vb + 3 < VV){
          *(float4*)(orow + vb) = make_float4(l4v[0],l4v[1],l4v[2],l4v[3]);
        } else {
          #pragma unroll
          for (int r=0;r<4;++r){
            int v = vb + r;
            if (v < VV) orow[v] = l4v[r]; else l4v[r] = -1e30f;
          }
        }
        #pragma unroll
        for (int i=0;i<4;++i) pm = fmaxf(pm, l4v[i]);
        #pragma unroll
        for (int i=0;i<4;++i) ps += (l4v[i] > -5e29f) ? __expf(l4v[i]-pm) : 0.f;
      }
      #pragma unroll
      for (int off=16; off<=32; off<<=1){
        float mo = __shfl_xor(pm, off);
        float so = __shfl_xor(ps, off);
        float nm = fmaxf(pm, mo);
        ps = ps*__expf(pm-nm) + so*__expf(mo-nm);
        pm = nm;
      }
      if (lgp == 0 && lm < 8) wred[wid][lm] = make_float2(pm, ps);
    }
    __syncthreads();
    if (tid < 8){
      float m = -1e30f, s = 0.f;
      #pragma unroll
      for (int w=0; w<8; ++w){
        float2 e = wred[w][tid];
        float nm = fmaxf(m, e.x);
        s = s*__expf(m-nm) + e.y*__expf(e.x-nm);
        m = nm;
      }
      *(float2*)(ws + OFF_PART + (t&1)*4096 + (bid*8 + tid)*2) = make_float2(m, s);
    }
    __syncthreads();
    if (tid == 0)
      __hip_atomic_store(&flags[bid*32], (uint_t)(t+1), __ATOMIC_RELEASE, __HIP_MEMORY_SCOPE_AGENT);

    // ---- slack: prepare t+1 (EC, cbPC, MFMAs, Lh preload) ----
    if (t < TT-1){
      int tn = t + 1;
      {
        int b = tid >> 6, l64 = tid & 63;
        int m8 = l64 * 8;
        int row = tn*8 + b;
        int ul = ulS[b];
        const ushort_t* Crow = (const ushort_t*)(ws + OFF_C) + ((size_t)row*UU)*512 + m8;
        float acc[8];
        #pragma unroll
        for (int i=0;i<8;++i) acc[i]=0.f;
        for (int u=0; u<ul; ++u){
          float su = suL[b][u];
          uint4 c0 = *(const uint4*)(Crow + (size_t)u*512);
          uint_t cc[4] = {c0.x,c0.y,c0.z,c0.w};
          #pragma unroll
          for (int q=0;q<4;++q){
            acc[2*q]   += su * __uint_as_float((cc[q] & 0xffffu) << 16);
            acc[2*q+1] += su * __uint_as_float((cc[q] >> 16) << 16);
          }
        }
        #pragma unroll
        for (int q=0;q<4;++q)
          cbEC[b*260 + l64*4 + q] = (uint_t)to_bf16(acc[2*q]) | ((uint_t)to_bf16(acc[2*q+1]) << 16);
        const float* PCrow = ws + OFF_PC + (size_t)row*512 + m8;
        float4 p0 = *(const float4*)PCrow;
        float4 p1 = *(const float4*)(PCrow + 4);
        cbPC[b*260 + l64*4 + 0] = (uint_t)to_bf16(p0.x) | ((uint_t)to_bf16(p0.y) << 16);
        cbPC[b*260 + l64*4 + 1] = (uint_t)to_bf16(p0.z) | ((uint_t)to_bf16(p0.w) << 16);
        cbPC[b*260 + l64*4 + 2] = (uint_t)to_bf16(p1.x) | ((uint_t)to_bf16(p1.y) << 16);
        cbPC[b*260 + l64*4 + 3] = (uint_t)to_bf16(p1.z) | ((uint_t)to_bf16(p1.w) << 16);
      }
      __syncthreads();
      LPC = (f32x4){0.f,0.f,0.f,0.f};
      LEC = (f32x4){0.f,0.f,0.f,0.f};
      #pragma unroll
      for (int ks=0; ks<16; ++ks){
        s16x8 av = *(const s16x8*)(ap0 + ks*32);
        s16x8 bp = *(const s16x8*)(cbrowP + ks*16);
        s16x8 be = *(const s16x8*)(cbrowE + ks*16);
        LPC = __builtin_amdgcn_mfma_f32_16x16x32_bf16(av, bp, LPC, 0, 0, 0);
        LEC = __builtin_amdgcn_mfma_f32_16x16x32_bf16(av, be, LEC, 0, 0, 0);
      }
      if (lm < 8){
        const float* orow = out + ((size_t)(lm*TT + tn))*VV;
        int vb = vbase + lgp*4;
        #pragma unroll
        for (int r=0;r<4;++r){ int v = vb + r; Lh4[r] = (v < VV) ? orow[v] : 0.f; }
      }
    }
  }
}

// ---------------- finals ----------------

__global__ void k_sub2(const float* __restrict__ ws, float* __restrict__ out){
  int v = blockIdx.x*256 + threadIdx.x;
  int tb = blockIdx.y;
  int t = tb >> 3, b = tb & 7;
  if (v < VV) out[(size_t)(b*TT+t)*VV + v] -= ws[OFF_LSE + tb];
}

__global__ void k_suw2(const int* __restrict__ word2utt, const float* __restrict__ ws,
                       float* __restrict__ out){
  int row = blockIdx.x;   // t*8+b
  int t = row >> 3, b = row & 7;
  int tid = threadIdx.x;
  for (int w=tid; w<WW; w+=256){
    int seg = word2utt[b*WW + w];
    float su = out[SU_OFF + (b*TT+t)*UU + seg];
    float pw = ws[OFF_SW + row*WW + w];
    out[SUW_OFF + (b*TT+t)*WW + w] = su*pw;
  }
}

extern "C" void kernel_launch(void* const* d_in, const int* in_sizes, int n_in,
                              void* d_out, int out_size, void* d_ws, size_t ws_size,
                              hipStream_t stream) {
  const int*   target   = (const int*)d_in[0];
  const float* u_output = (const float*)d_in[1];
  const float* w_output = (const float*)d_in[2];
  const int*   u_len    = (const int*)d_in[3];
  const int*   w_len    = (const int*)d_in[4];
  const int*   word2utt = (const int*)d_in[5];
  const float* emb      = (const float*)d_in[6];
  const float* W_ih     = (const float*)d_in[7];
  const float* W_hh     = (const float*)d_in[8];
  const float* b_ih     = (const float*)d_in[9];
  const float* b_hh     = (const float*)d_in[10];
  const float* Wu       = (const float*)d_in[11];
  const float* Ww       = (const float*)d_in[13];
  const float* Wo       = (const float*)d_in[15];
  const float* bo       = (const float*)d_in[16];
  const float* Wd       = (const float*)d_in[17];
  const float* Wy       = (const float*)d_in[18];
  const float* Ws       = (const float*)d_in[19];
  const float* bs       = (const float*)d_in[20];
  float* out = (float*)d_out;
  float* ws  = (float*)d_ws;
  ushort_t* wov = (ushort_t*)(ws + OFF_WOV);
  ushort_t* hbt = (ushort_t*)(ws + OFF_HBT);

  // --- reset barrier flags (per launch, graph-replay safe) ---
  hipMemsetAsync(ws + OFF_SYNC, 0, 16384*sizeof(float), stream);

  // --- batched precompute ---
  hipLaunchKernelGGL(k_y, dim3(512), dim3(256), 0, stream, target, emb, Wy, ws);
  hipLaunchKernelGGL((k_gemm_b<1>), dim3(24,8,1), dim3(256), 0, stream,
                     ws+OFF_YALL, 256, 0, W_ih, 256, 0, b_ih, ws+OFF_GI, 1536, 0, 256);
  hipLaunchKernelGGL(k_h0, dim3(16), dim3(256), 0, stream, u_output, u_len, ws);
  hipLaunchKernelGGL(k_wovc, dim3(7520), dim3(256), 0, stream, Wo, wov);
  hipMemsetAsync(ws + OFF_WV, 0, 1536*sizeof(float), stream);
  hipLaunchKernelGGL(k_wv, dim3(235), dim3(256), 0, stream, Wo, bo, Wd, ws+OFF_WV);

  // --- GRU hidden chain: persistent, split-K, single-hop barrier (+hbt tail) ---
  hipLaunchKernelGGL(k_gru_persist, dim3(NBG), dim3(1024), 0, stream, W_hh, b_hh, ws);

  // --- batched post-h precompute ---
  hipLaunchKernelGGL(k_lh_mfma, dim3(235, 4), dim3(256), 0, stream, Wo, bo, hbt, out);
  hipLaunchKernelGGL((k_gemm_b<0>), dim3(8,8,1), dim3(256), 0, stream,
                     ws+OFF_HALL, 512, 0, Wu, 512, 0, (const float*)nullptr, ws+OFF_HU, 512, 0, 512);
  hipLaunchKernelGGL((k_gemm_b<0>), dim3(8,8,1), dim3(256), 0, stream,
                     ws+OFF_HALL, 512, 0, Ww, 512, 0, (const float*)nullptr, ws+OFF_HW, 512, 0, 512);
  hipLaunchKernelGGL(k_hdots, dim3(256), dim3(256), 0, stream, Ws, ws);
  hipLaunchKernelGGL(k_p, dim3(512), dim3(256), 0, stream, u_output, u_len, ws);
  hipLaunchKernelGGL((k_gemm_b<1>), dim3(8,1,8), dim3(256), 0, stream,
                     ws+OFF_HW, 4096, 512, w_output, 512, 262144, (const float*)nullptr,
                     ws+OFF_SW, 4096, 512, 512);
  hipLaunchKernelGGL(k_pw, dim3(512), dim3(256), 0, stream, word2utt, w_len, ws);
  hipLaunchKernelGGL(k_C, dim3(512), dim3(256), 0, stream,
                     w_output, w_len, u_len, word2utt, ws);

  // --- serial decode: 235 workers + 1 leader, pipelined MFMA ---
  hipLaunchKernelGGL(k_decode_persist, dim3(NDB+1), dim3(512), 0, stream,
                     u_len, bs, wov, ws, out);

  // --- batched finals ---
  hipLaunchKernelGGL(k_sub2, dim3(118, 512), dim3(256), 0, stream, ws, out);
  hipLaunchKernelGGL(k_suw2, dim3(512), dim3(256), 0, stream, word2utt, ws, out);
}